// Round 1
// baseline (176.107 us; speedup 1.0000x reference)
//
#include <hip/hip_runtime.h>

// 3x3 VALID conv, stride 1, cross-correlation.
// x: (64, 224, 224) fp32, w: (128, 64, 3, 3) fp32, out: (128, 222, 222) fp32.
//
// Round 0: fp32 direct conv (no fp32 MFMA on CDNA4 -> VALU path).
// Register blocking: each thread computes CO_T=8 output channels x ROWS=2
// output rows at one column -> per input channel: 12 x-loads, 144 FMAs.
// Weight loads are wave-uniform -> scalar (s_load) broadcasts.

#define C_IN   64
#define H_IN   224
#define W_IN   224
#define C_OUT  128
#define H_OUT  222
#define W_OUT  222
#define CO_T   8
#define ROWS   2

__global__ __launch_bounds__(256)
void conv3x3_kernel(const float* __restrict__ x,
                    const float* __restrict__ w,
                    float* __restrict__ out)
{
    const int NP = (H_OUT / ROWS) * W_OUT;   // 111 * 222 = 24642 (row-pair, col) combos
    int p = blockIdx.x * 256 + threadIdx.x;
    if (p >= NP) return;

    const int ow  = p % W_OUT;
    const int oh  = (p / W_OUT) * ROWS;
    const int co0 = blockIdx.y * CO_T;

    float acc[CO_T][ROWS];
    #pragma unroll
    for (int u = 0; u < CO_T; ++u)
        #pragma unroll
        for (int r = 0; r < ROWS; ++r)
            acc[u][r] = 0.0f;

    for (int c = 0; c < C_IN; ++c) {
        // x window: rows oh..oh+ROWS+1 (4 rows), cols ow..ow+2
        float xv[ROWS + 2][3];
        const float* xc = x + (c * H_IN + oh) * W_IN + ow;
        #pragma unroll
        for (int r = 0; r < ROWS + 2; ++r)
            #pragma unroll
            for (int j = 0; j < 3; ++j)
                xv[r][j] = xc[r * W_IN + j];

        #pragma unroll
        for (int u = 0; u < CO_T; ++u) {
            const float* wp = w + ((co0 + u) * C_IN + c) * 9;  // uniform -> s_load
            #pragma unroll
            for (int i = 0; i < 3; ++i) {
                #pragma unroll
                for (int j = 0; j < 3; ++j) {
                    const float wv = wp[i * 3 + j];
                    #pragma unroll
                    for (int r = 0; r < ROWS; ++r)
                        acc[u][r] += xv[r + i][j] * wv;
                }
            }
        }
    }

    #pragma unroll
    for (int u = 0; u < CO_T; ++u)
        #pragma unroll
        for (int r = 0; r < ROWS; ++r)
            out[(co0 + u) * (H_OUT * W_OUT) + (oh + r) * W_OUT + ow] = acc[u][r];
}

extern "C" void kernel_launch(void* const* d_in, const int* in_sizes, int n_in,
                              void* d_out, int out_size, void* d_ws, size_t ws_size,
                              hipStream_t stream)
{
    const float* x = (const float*)d_in[0];
    const float* w = (const float*)d_in[1];
    float* out     = (float*)d_out;

    const int NP = (H_OUT / ROWS) * W_OUT;           // 24642
    dim3 grid((NP + 255) / 256, C_OUT / CO_T);       // (97, 16)
    conv3x3_kernel<<<grid, 256, 0, stream>>>(x, w, out);
}

// Round 2
// 116.604 us; speedup vs baseline: 1.5103x; 1.5103x over previous
//
#include <hip/hip_runtime.h>
#include <hip/hip_bf16.h>

// 3x3 VALID conv via bf16 MFMA implicit GEMM.
// x: (64,224,224) fp32, w: (128,64,3,3) fp32, out: (128,222,222) fp32.
//
// Decompose over the 9 filter taps: for each (i,j), a K=64 GEMM
//   C[co][oh][ow] += W[co][c][i][j] * x[c][oh+i][ow+j]
// Pre-pass 1: wt[ij][co][c] bf16 (c contiguous = MFMA K).
// Pre-pass 2: xt[h][w][c]   bf16, zero-padded to 226x226 (tiles never OOB).
// Conv: block = 64 co x 8 oh x 16 ow; x tile staged in LDS [10][18][72]
// (c padded 64->72: even bank spread for ds_read_b128, 16B-aligned).
// mfma_f32_16x16x32_bf16: A lane->co (m=lane&15, k=quad*8+j),
// B lane->ow, D: col(ow)=lane&15, row(co)=quad*4+reg.

#define H_IN   224
#define W_IN   224
#define C_INN  64
#define C_OUT  128
#define H_OUT  222
#define W_OUT  222
#define XP     226   // padded spatial extent of xt
#define CPAD   72    // padded c stride in LDS

typedef __attribute__((ext_vector_type(8))) short bf16x8;
typedef __attribute__((ext_vector_type(4))) float f32x4;

__global__ __launch_bounds__(256)
void transform_w_kernel(const float* __restrict__ w, __hip_bfloat16* __restrict__ wt)
{
    int idx = blockIdx.x * 256 + threadIdx.x;     // [ij][co][c], 9*128*64
    if (idx < 9 * 128 * 64) {
        int ij  = idx >> 13;
        int rem = idx & 8191;
        int co  = rem >> 6;
        int c   = rem & 63;
        wt[idx] = __float2bfloat16(w[(co * 64 + c) * 9 + ij]);
    }
}

__global__ __launch_bounds__(256)
void transpose_x_kernel(const float* __restrict__ x, __hip_bfloat16* __restrict__ xt)
{
    __shared__ __hip_bfloat16 tile[64 * CPAD];    // [w][c], c padded
    int w0 = blockIdx.x * 64;
    int h  = blockIdx.y;                          // 0..225
    int c  = threadIdx.x >> 2;                    // 0..63
    int wl = (threadIdx.x & 3) * 16;
    #pragma unroll
    for (int k = 0; k < 16; ++k) {
        int w = w0 + wl + k;
        float v = (h < H_IN && w < W_IN) ? x[(c * H_IN + h) * W_IN + w] : 0.0f;
        tile[(wl + k) * CPAD + c] = __float2bfloat16(v);
    }
    __syncthreads();
    int w  = threadIdx.x >> 2;                    // 0..63
    int cl = (threadIdx.x & 3) * 16;              // 0,16,32,48
    if (w0 + w < XP) {
        const float4* s = (const float4*)(tile + w * CPAD + cl);   // 16B aligned
        float4*       d = (float4*)(xt + (h * XP + (w0 + w)) * 64 + cl);
        d[0] = s[0];
        d[1] = s[1];
    }
}

__global__ __launch_bounds__(256)
void conv_mfma_kernel(const __hip_bfloat16* __restrict__ xt,
                      const __hip_bfloat16* __restrict__ wt,
                      float* __restrict__ out)
{
    __shared__ __hip_bfloat16 xs[10 * 18 * CPAD];  // [row][wc][c] = 25,920 B
    const int ow0 = blockIdx.x * 16;
    const int oh0 = blockIdx.y * 8;
    const int co0 = blockIdx.z * 64;
    const int tid = threadIdx.x;

    // Stage x tile: rows oh0..oh0+9, cols ow0..ow0+17, all 64 c (bf16).
    // 1440 chunks of 16B; global side contiguous per (row,wc) pixel.
    for (int q = tid; q < 10 * 18 * 8; q += 256) {
        int sub = q & 7;
        int pix = q >> 3;
        int row = pix / 18;
        int wc  = pix - row * 18;
        const float4* s = (const float4*)(xt + ((oh0 + row) * XP + (ow0 + wc)) * 64 + sub * 8);
        float4*       d = (float4*)(xs + (row * 18 + wc) * CPAD + sub * 8);
        *d = *s;
    }
    __syncthreads();

    const int wave = tid >> 6;
    const int lane = tid & 63;
    const int lq   = lane >> 4;    // quad 0..3
    const int lm   = lane & 15;
    const int r0   = wave * 2;     // this wave's 2 output rows

    f32x4 acc[2][4] = {};

    #pragma unroll 1
    for (int ij = 0; ij < 9; ++ij) {
        const int i = ij / 3;
        const int j = ij - i * 3;
        // A fragments: 2 k-steps x 4 co-subtiles (weights, L1/L2-hot)
        bf16x8 afr[2][4];
        #pragma unroll
        for (int t = 0; t < 2; ++t)
            #pragma unroll
            for (int ms = 0; ms < 4; ++ms)
                afr[t][ms] = *(const bf16x8*)(wt +
                    ((ij * 128 + co0 + ms * 16 + lm) * 64 + t * 32 + lq * 8));
        #pragma unroll
        for (int rr = 0; rr < 2; ++rr) {
            const int r = r0 + rr;
            #pragma unroll
            for (int t = 0; t < 2; ++t) {
                bf16x8 bfr = *(const bf16x8*)(xs +
                    ((i + r) * 18 + lm + j) * CPAD + t * 32 + lq * 8);
                #pragma unroll
                for (int ms = 0; ms < 4; ++ms)
                    acc[rr][ms] = __builtin_amdgcn_mfma_f32_16x16x32_bf16(
                        afr[t][ms], bfr, acc[rr][ms], 0, 0, 0);
            }
        }
    }

    // Epilogue: D col(ow)=lm, row(co offset)=lq*4+d
    #pragma unroll
    for (int rr = 0; rr < 2; ++rr) {
        int oh = oh0 + r0 + rr;
        int ow = ow0 + lm;
        if (oh < H_OUT && ow < W_OUT) {
            #pragma unroll
            for (int ms = 0; ms < 4; ++ms) {
                int co = co0 + ms * 16 + lq * 4;
                #pragma unroll
                for (int d = 0; d < 4; ++d)
                    out[(co + d) * (H_OUT * W_OUT) + oh * W_OUT + ow] = acc[rr][ms][d];
            }
        }
    }
}

extern "C" void kernel_launch(void* const* d_in, const int* in_sizes, int n_in,
                              void* d_out, int out_size, void* d_ws, size_t ws_size,
                              hipStream_t stream)
{
    const float* x = (const float*)d_in[0];
    const float* w = (const float*)d_in[1];
    float* out     = (float*)d_out;

    __hip_bfloat16* xt = (__hip_bfloat16*)d_ws;                      // 226*226*64*2 = 6,537,728 B
    __hip_bfloat16* wt = (__hip_bfloat16*)((char*)d_ws + (size_t)XP * XP * 64 * 2); // 147,456 B

    transform_w_kernel<<<288, 256, 0, stream>>>(w, wt);
    transpose_x_kernel<<<dim3(4, XP), 256, 0, stream>>>(x, xt);
    conv_mfma_kernel<<<dim3(14, 28, 2), 256, 0, stream>>>(xt, wt, out);
}

// Round 4
// 109.262 us; speedup vs baseline: 1.6118x; 1.0672x over previous
//
#include <hip/hip_runtime.h>
#include <hip/hip_bf16.h>

// 3x3 VALID conv via bf16 MFMA implicit GEMM.
// x: (64,224,224) fp32, w: (128,64,3,3) fp32, out: (128,222,222) fp32.
//
// R4: R2's proven conv + weight kernels verbatim; only the x-transpose is
// rewritten for coalescing (R2's read pattern was lane-stride-64-floats ->
// one cache line per lane per instruction).
//  transpose: per block 64 w x 64 c for one h row. Phase 1: float4 reads
//  along w (lanes contiguous), LDS tile[c][w]. Phase 2: 16 c per thread
//  from LDS, contiguous float4x2 stores to xt[h][w][c].

#define H_IN   224
#define W_IN   224
#define C_OUT  128
#define H_OUT  222
#define W_OUT  222
#define XP     226   // padded spatial extent of xt
#define CPAD   72    // padded c stride in conv LDS
#define TW     68    // padded w stride in transpose LDS

typedef __attribute__((ext_vector_type(8))) short bf16x8;
typedef __attribute__((ext_vector_type(4))) float f32x4;

static __device__ __forceinline__ unsigned short f2bs(float f) {
    union { __hip_bfloat16 h; unsigned short u; } cv;
    cv.h = __float2bfloat16(f);
    return cv.u;
}

__global__ __launch_bounds__(256)
void transform_w_kernel(const float* __restrict__ w, __hip_bfloat16* __restrict__ wt)
{
    int idx = blockIdx.x * 256 + threadIdx.x;     // [ij][co][c], 9*128*64
    if (idx < 9 * 128 * 64) {
        int ij  = idx >> 13;
        int rem = idx & 8191;
        int co  = rem >> 6;
        int c   = rem & 63;
        wt[idx] = __float2bfloat16(w[(co * 64 + c) * 9 + ij]);
    }
}

__global__ __launch_bounds__(256)
void transpose_x_kernel(const float* __restrict__ x, __hip_bfloat16* __restrict__ xt)
{
    __shared__ __align__(16) unsigned short tile[64 * TW];   // [c][w_local]
    const int h  = blockIdx.y;                 // 0..225
    const int w0 = blockIdx.x * 64;            // 0,64,128,192
    const int t  = threadIdx.x;

    // Phase 1: coalesced float4 reads along w; zeros for padded h/w.
    {
        const int wq = (t & 15) * 4;           // 0..60 (lanes contiguous in w)
        const int c0 = t >> 4;                 // 0..15
        #pragma unroll
        for (int p = 0; p < 4; ++p) {
            const int c  = c0 + p * 16;
            const int wg = w0 + wq;
            float4 v = make_float4(0.f, 0.f, 0.f, 0.f);
            if (h < H_IN && wg < W_IN)         // wg%4==0, W_IN%4==0 -> all-or-nothing
                v = *(const float4*)(x + ((size_t)c * H_IN + h) * W_IN + wg);
            ushort4 b;
            b.x = f2bs(v.x); b.y = f2bs(v.y); b.z = f2bs(v.z); b.w = f2bs(v.w);
            *(ushort4*)(tile + c * TW + wq) = b;   // (c*136 + wq*2) % 8 == 0
        }
    }
    __syncthreads();

    // Phase 2: gather 16 c per thread from LDS, contiguous 16B/lane stores.
    {
        const int wl = t >> 2;                 // 0..63
        const int cq = (t & 3) * 16;           // 0,16,32,48
        const int wg = w0 + wl;
        if (wg < XP) {
            alignas(16) unsigned short r[16];
            #pragma unroll
            for (int k = 0; k < 16; ++k)
                r[k] = tile[(cq + k) * TW + wl];
            float4* d = (float4*)((unsigned short*)xt + ((size_t)h * XP + wg) * 64 + cq);
            d[0] = ((const float4*)r)[0];
            d[1] = ((const float4*)r)[1];
        }
    }
}

__global__ __launch_bounds__(256)
void conv_mfma_kernel(const __hip_bfloat16* __restrict__ xt,
                      const __hip_bfloat16* __restrict__ wt,
                      float* __restrict__ out)
{
    __shared__ __hip_bfloat16 xs[10 * 18 * CPAD];  // [row][wc][c] = 25,920 B
    const int ow0 = blockIdx.x * 16;
    const int oh0 = blockIdx.y * 8;
    const int co0 = blockIdx.z * 64;
    const int tid = threadIdx.x;

    // Stage x tile: rows oh0..oh0+9, cols ow0..ow0+17, all 64 c (bf16).
    for (int q = tid; q < 10 * 18 * 8; q += 256) {
        int sub = q & 7;
        int pix = q >> 3;
        int row = pix / 18;
        int wc  = pix - row * 18;
        const float4* s = (const float4*)(xt + ((oh0 + row) * XP + (ow0 + wc)) * 64 + sub * 8);
        float4*       d = (float4*)(xs + (row * 18 + wc) * CPAD + sub * 8);
        *d = *s;
    }
    __syncthreads();

    const int wave = tid >> 6;
    const int lane = tid & 63;
    const int lq   = lane >> 4;    // quad 0..3
    const int lm   = lane & 15;
    const int r0   = wave * 2;     // this wave's 2 output rows

    f32x4 acc[2][4] = {};

    #pragma unroll 1
    for (int ij = 0; ij < 9; ++ij) {
        const int i = ij / 3;
        const int j = ij - i * 3;
        bf16x8 afr[2][4];
        #pragma unroll
        for (int t = 0; t < 2; ++t)
            #pragma unroll
            for (int ms = 0; ms < 4; ++ms)
                afr[t][ms] = *(const bf16x8*)(wt +
                    ((ij * 128 + co0 + ms * 16 + lm) * 64 + t * 32 + lq * 8));
        #pragma unroll
        for (int rr = 0; rr < 2; ++rr) {
            const int r = r0 + rr;
            #pragma unroll
            for (int t = 0; t < 2; ++t) {
                bf16x8 bfr = *(const bf16x8*)(xs +
                    ((i + r) * 18 + lm + j) * CPAD + t * 32 + lq * 8);
                #pragma unroll
                for (int ms = 0; ms < 4; ++ms)
                    acc[rr][ms] = __builtin_amdgcn_mfma_f32_16x16x32_bf16(
                        afr[t][ms], bfr, acc[rr][ms], 0, 0, 0);
            }
        }
    }

    // Epilogue: D col(ow)=lm, row(co offset)=lq*4+d
    #pragma unroll
    for (int rr = 0; rr < 2; ++rr) {
        int oh = oh0 + r0 + rr;
        int ow = ow0 + lm;
        if (oh < H_OUT && ow < W_OUT) {
            #pragma unroll
            for (int ms = 0; ms < 4; ++ms) {
                int co = co0 + ms * 16 + lq * 4;
                #pragma unroll
                for (int d = 0; d < 4; ++d)
                    out[(co + d) * (H_OUT * W_OUT) + oh * W_OUT + ow] = acc[rr][ms][d];
            }
        }
    }
}

extern "C" void kernel_launch(void* const* d_in, const int* in_sizes, int n_in,
                              void* d_out, int out_size, void* d_ws, size_t ws_size,
                              hipStream_t stream)
{
    const float* x = (const float*)d_in[0];
    const float* w = (const float*)d_in[1];
    float* out     = (float*)d_out;

    __hip_bfloat16* xt = (__hip_bfloat16*)d_ws;                      // 226*226*64*2 B
    __hip_bfloat16* wt = (__hip_bfloat16*)((char*)d_ws + (size_t)XP * XP * 64 * 2);

    transform_w_kernel<<<288, 256, 0, stream>>>(w, wt);
    transpose_x_kernel<<<dim3(4, XP), 256, 0, stream>>>(x, xt);
    conv_mfma_kernel<<<dim3(14, 28, 2), 256, 0, stream>>>(xt, wt, out);
}

// Round 5
// 108.242 us; speedup vs baseline: 1.6270x; 1.0094x over previous
//
#include <hip/hip_runtime.h>
#include <hip/hip_bf16.h>

// 3x3 VALID conv via bf16 MFMA implicit GEMM.
// x: (64,224,224) fp32, w: (128,64,3,3) fp32, out: (128,222,222) fp32.
//
// R5: identical to R4 except conv tap loop `#pragma unroll 1` -> `unroll 3`
// (batch weight-fragment loads across 3 taps to hide global-load latency;
// R3's crash is attributed to __launch_bounds__(256,3) forcing spills, so
// no VGPR cap here).

#define H_IN   224
#define W_IN   224
#define C_OUT  128
#define H_OUT  222
#define W_OUT  222
#define XP     226   // padded spatial extent of xt
#define CPAD   72    // padded c stride in conv LDS
#define TW     68    // padded w stride in transpose LDS

typedef __attribute__((ext_vector_type(8))) short bf16x8;
typedef __attribute__((ext_vector_type(4))) float f32x4;

static __device__ __forceinline__ unsigned short f2bs(float f) {
    union { __hip_bfloat16 h; unsigned short u; } cv;
    cv.h = __float2bfloat16(f);
    return cv.u;
}

__global__ __launch_bounds__(256)
void transform_w_kernel(const float* __restrict__ w, __hip_bfloat16* __restrict__ wt)
{
    int idx = blockIdx.x * 256 + threadIdx.x;     // [ij][co][c], 9*128*64
    if (idx < 9 * 128 * 64) {
        int ij  = idx >> 13;
        int rem = idx & 8191;
        int co  = rem >> 6;
        int c   = rem & 63;
        wt[idx] = __float2bfloat16(w[(co * 64 + c) * 9 + ij]);
    }
}

__global__ __launch_bounds__(256)
void transpose_x_kernel(const float* __restrict__ x, __hip_bfloat16* __restrict__ xt)
{
    __shared__ __align__(16) unsigned short tile[64 * TW];   // [c][w_local]
    const int h  = blockIdx.y;                 // 0..225
    const int w0 = blockIdx.x * 64;            // 0,64,128,192
    const int t  = threadIdx.x;

    // Phase 1: coalesced float4 reads along w; zeros for padded h/w.
    {
        const int wq = (t & 15) * 4;           // 0..60 (lanes contiguous in w)
        const int c0 = t >> 4;                 // 0..15
        #pragma unroll
        for (int p = 0; p < 4; ++p) {
            const int c  = c0 + p * 16;
            const int wg = w0 + wq;
            float4 v = make_float4(0.f, 0.f, 0.f, 0.f);
            if (h < H_IN && wg < W_IN)         // wg%4==0, W_IN%4==0 -> all-or-nothing
                v = *(const float4*)(x + ((size_t)c * H_IN + h) * W_IN + wg);
            ushort4 b;
            b.x = f2bs(v.x); b.y = f2bs(v.y); b.z = f2bs(v.z); b.w = f2bs(v.w);
            *(ushort4*)(tile + c * TW + wq) = b;   // (c*136 + wq*2) % 8 == 0
        }
    }
    __syncthreads();

    // Phase 2: gather 16 c per thread from LDS, contiguous 16B/lane stores.
    {
        const int wl = t >> 2;                 // 0..63
        const int cq = (t & 3) * 16;           // 0,16,32,48
        const int wg = w0 + wl;
        if (wg < XP) {
            alignas(16) unsigned short r[16];
            #pragma unroll
            for (int k = 0; k < 16; ++k)
                r[k] = tile[(cq + k) * TW + wl];
            float4* d = (float4*)((unsigned short*)xt + ((size_t)h * XP + wg) * 64 + cq);
            d[0] = ((const float4*)r)[0];
            d[1] = ((const float4*)r)[1];
        }
    }
}

__global__ __launch_bounds__(256)
void conv_mfma_kernel(const __hip_bfloat16* __restrict__ xt,
                      const __hip_bfloat16* __restrict__ wt,
                      float* __restrict__ out)
{
    __shared__ __hip_bfloat16 xs[10 * 18 * CPAD];  // [row][wc][c] = 25,920 B
    const int ow0 = blockIdx.x * 16;
    const int oh0 = blockIdx.y * 8;
    const int co0 = blockIdx.z * 64;
    const int tid = threadIdx.x;

    // Stage x tile: rows oh0..oh0+9, cols ow0..ow0+17, all 64 c (bf16).
    for (int q = tid; q < 10 * 18 * 8; q += 256) {
        int sub = q & 7;
        int pix = q >> 3;
        int row = pix / 18;
        int wc  = pix - row * 18;
        const float4* s = (const float4*)(xt + ((oh0 + row) * XP + (ow0 + wc)) * 64 + sub * 8);
        float4*       d = (float4*)(xs + (row * 18 + wc) * CPAD + sub * 8);
        *d = *s;
    }
    __syncthreads();

    const int wave = tid >> 6;
    const int lane = tid & 63;
    const int lq   = lane >> 4;    // quad 0..3
    const int lm   = lane & 15;
    const int r0   = wave * 2;     // this wave's 2 output rows

    f32x4 acc[2][4] = {};

    #pragma unroll 3
    for (int ij = 0; ij < 9; ++ij) {
        const int i = ij / 3;
        const int j = ij - i * 3;
        bf16x8 afr[2][4];
        #pragma unroll
        for (int t = 0; t < 2; ++t)
            #pragma unroll
            for (int ms = 0; ms < 4; ++ms)
                afr[t][ms] = *(const bf16x8*)(wt +
                    ((ij * 128 + co0 + ms * 16 + lm) * 64 + t * 32 + lq * 8));
        #pragma unroll
        for (int rr = 0; rr < 2; ++rr) {
            const int r = r0 + rr;
            #pragma unroll
            for (int t = 0; t < 2; ++t) {
                bf16x8 bfr = *(const bf16x8*)(xs +
                    ((i + r) * 18 + lm + j) * CPAD + t * 32 + lq * 8);
                #pragma unroll
                for (int ms = 0; ms < 4; ++ms)
                    acc[rr][ms] = __builtin_amdgcn_mfma_f32_16x16x32_bf16(
                        afr[t][ms], bfr, acc[rr][ms], 0, 0, 0);
            }
        }
    }

    // Epilogue: D col(ow)=lm, row(co offset)=lq*4+d
    #pragma unroll
    for (int rr = 0; rr < 2; ++rr) {
        int oh = oh0 + r0 + rr;
        int ow = ow0 + lm;
        if (oh < H_OUT && ow < W_OUT) {
            #pragma unroll
            for (int ms = 0; ms < 4; ++ms) {
                int co = co0 + ms * 16 + lq * 4;
                #pragma unroll
                for (int d = 0; d < 4; ++d)
                    out[(co + d) * (H_OUT * W_OUT) + oh * W_OUT + ow] = acc[rr][ms][d];
            }
        }
    }
}

extern "C" void kernel_launch(void* const* d_in, const int* in_sizes, int n_in,
                              void* d_out, int out_size, void* d_ws, size_t ws_size,
                              hipStream_t stream)
{
    const float* x = (const float*)d_in[0];
    const float* w = (const float*)d_in[1];
    float* out     = (float*)d_out;

    __hip_bfloat16* xt = (__hip_bfloat16*)d_ws;                      // 226*226*64*2 B
    __hip_bfloat16* wt = (__hip_bfloat16*)((char*)d_ws + (size_t)XP * XP * 64 * 2);

    transform_w_kernel<<<288, 256, 0, stream>>>(w, wt);
    transpose_x_kernel<<<dim3(4, XP), 256, 0, stream>>>(x, xt);
    conv_mfma_kernel<<<dim3(14, 28, 2), 256, 0, stream>>>(xt, wt, out);
}